// Round 10
// baseline (538.368 us; speedup 1.0000x reference)
//
#include <hip/hip_runtime.h>

// UAG_RNN v14: v13's 16-wave colscan with CORRECT sync. v13 raced: with the
// channel-split, the full-64ch fb read includes the partner wave's half, but
// fb was read pre-barrier while the partner's write was only wave-fenced ->
// garbage state -> inf. Fix: ONE barrier per step, placed AFTER the state
// writes; all stt reads (fb and ft) happen at step start, safely behind every
// wave's previous-step writes. Same s_barrier count per step as v12.
// 1024 threads = 16 waves = 4/SIMD: wave = (row-group rg, channel-half ch),
// 12 MFMAs/step/wave, 4 independent streams per SIMD (ILP experiment).
// B=8, C=64, H=128, W=128.

#define B_ 8
#define C_ 64
#define H_ 128
#define W_ 128
#define HW_ (H_*W_)      // 16384
#define CHW_ (C_*HW_)    // 1048576
#define TOT_ (B_*CHW_)   // 8388608

typedef __attribute__((ext_vector_type(8))) short bfrag;
typedef __attribute__((ext_vector_type(4))) float f4_t;

#define LDS_BARRIER() do { \
    __builtin_amdgcn_sched_barrier(0); \
    asm volatile("s_waitcnt lgkmcnt(0)\n\ts_barrier" ::: "memory"); \
    __builtin_amdgcn_sched_barrier(0); \
} while (0)

#define WAVE_LDS_FENCE() do { \
    asm volatile("s_waitcnt lgkmcnt(0)" ::: "memory"); \
    __builtin_amdgcn_sched_barrier(0); \
} while (0)

__device__ inline unsigned short bfr(float f) {
    unsigned int u = __float_as_uint(f);
    u += 0x7fffu + ((u >> 16) & 1u);
    return (unsigned short)(u >> 16);
}
__device__ inline float b2f(unsigned short u) {
    return __uint_as_float(((unsigned int)u) << 16);
}
__device__ inline float blo(unsigned int u) { return __uint_as_float(u << 16); }
__device__ inline float bhi(unsigned int u) { return __uint_as_float(u & 0xffff0000u); }
__device__ inline unsigned int cvtpk(float lo, float hi) {
    unsigned int r;
    asm("v_cvt_pk_bf16_f32 %0, %1, %2" : "=v"(r) : "v"(lo), "v"(hi));
    return r;
}
__device__ inline bfrag packf(float4 a, float4 b) {
    bfrag r;
    r[0]=(short)bfr(a.x); r[1]=(short)bfr(a.y); r[2]=(short)bfr(a.z); r[3]=(short)bfr(a.w);
    r[4]=(short)bfr(b.x); r[5]=(short)bfr(b.y); r[6]=(short)bfr(b.z); r[7]=(short)bfr(b.w);
    return r;
}
__device__ inline bfrag packfs(float4 a, float4 b, float s) {
    bfrag r;
    r[0]=(short)bfr(s*a.x); r[1]=(short)bfr(s*a.y); r[2]=(short)bfr(s*a.z); r[3]=(short)bfr(s*a.w);
    r[4]=(short)bfr(s*b.x); r[5]=(short)bfr(s*b.y); r[6]=(short)bfr(s*b.z); r[7]=(short)bfr(s*b.w);
    return r;
}
__device__ inline unsigned int relu2(unsigned int w) {
    unsigned int lo = (w & 0x8000u) ? 0u : (w & 0xffffu);
    unsigned int hi = (w & 0x80000000u) ? 0u : (w & 0xffff0000u);
    return lo | hi;
}
__device__ inline uint4 relu8(uint4 v) {
    v.x = relu2(v.x); v.y = relu2(v.y); v.z = relu2(v.z); v.w = relu2(v.w);
    return v;
}
// XOR slot swizzle for stt (rows of 64 shorts = 8 slots of 16B)
__device__ inline int swz(int r, int s) {
    return (((s >> 3) ^ (r & 7)) << 3) | (s & 7);
}
// y2t use-order channel swizzle for the 16-wave colscan:
// c = mtg*16 + q*4 + r  ->  pos = q*16 + (mtg>>1)*8 + (mtg&1)*4 + r
__device__ inline int newc2(int c) {
    return (((c >> 2) & 3) << 4) | (((c >> 5) & 1) << 3) | (((c >> 4) & 1) << 2) | (c & 3);
}

#define MFMA __builtin_amdgcn_mfma_f32_16x16x32_bf16

// x NCHW fp32 -> x2 NHWC bf16; y NCHW fp32 -> y2b NHWC bf16 + y2t WHC-swz bf16
__global__ void k_prep(const float* __restrict__ x, const float* __restrict__ y,
                       unsigned short* __restrict__ y2b, unsigned short* __restrict__ x2,
                       unsigned short* __restrict__ y2t) {
    __shared__ float t[64][65];
    int blk = blockIdx.x;
    int isx = blk >> 11; blk &= 2047;
    int b = blk >> 8, hw0 = (blk & 255) * 64;
    int cq = threadIdx.x >> 6, lo = threadIdx.x & 63;
    const float* ip = (isx ? x : y) + (size_t)b * CHW_;
#pragma unroll
    for (int p = 0; p < 16; p++) {
        int c = p * 4 + cq;
        t[c][lo] = ip[(size_t)c * HW_ + hw0 + lo];
    }
    __syncthreads();
    unsigned short* op = (isx ? x2 : y2b) + (size_t)b * CHW_;
#pragma unroll
    for (int p = 0; p < 16; p++) {
        int hw = p * 4 + cq;
        op[(size_t)(hw0 + hw) * 64 + lo] = bfr(t[lo][hw]);
    }
    if (!isx) {
        unsigned short* op2 = y2t + (size_t)b * CHW_;
        int lon = newc2(lo);
#pragma unroll
        for (int p = 0; p < 16; p++) {
            int hw = p * 4 + cq;
            int pos = hw0 + hw, h = pos >> 7, w = pos & 127;
            op2[(size_t)w * 8192 + h * 64 + lon] = bfr(t[lo][hw]);
        }
    }
}

// sum 4 bf16 NHWC dir buffers -> out NCHW fp32
__global__ void k_tb(const unsigned short* __restrict__ i0, const unsigned short* __restrict__ i1,
                     const unsigned short* __restrict__ i2, const unsigned short* __restrict__ i3,
                     float* __restrict__ outp) {
    __shared__ float t[64][65];
    int blk = blockIdx.x;
    int b = blk >> 8, hw0 = (blk & 255) * 64;
    int tid = threadIdx.x;
    size_t bb = (size_t)b * CHW_;
    int hwi = tid >> 4, c4 = (tid & 15) * 4;
#pragma unroll
    for (int p = 0; p < 4; p++) {
        int hw = p * 16 + hwi;
        size_t s = bb + (size_t)(hw0 + hw) * 64 + c4;
        uint2 u0 = *(const uint2*)(i0 + s);
        uint2 u1 = *(const uint2*)(i1 + s);
        uint2 u2 = *(const uint2*)(i2 + s);
        uint2 u3 = *(const uint2*)(i3 + s);
        float v0 = blo(u0.x) + blo(u1.x) + blo(u2.x) + blo(u3.x);
        float v1 = bhi(u0.x) + bhi(u1.x) + bhi(u2.x) + bhi(u3.x);
        float v2 = blo(u0.y) + blo(u1.y) + blo(u2.y) + blo(u3.y);
        float v3 = bhi(u0.y) + bhi(u1.y) + bhi(u2.y) + bhi(u3.y);
        t[hw][c4 + 0] = v0; t[hw][c4 + 1] = v1; t[hw][c4 + 2] = v2; t[hw][c4 + 3] = v3;
    }
    __syncthreads();
    float* op = outp + bb;
    int cq = tid >> 6, lo = tid & 63;
#pragma unroll
    for (int p = 0; p < 16; p++) {
        int c = p * 4 + cq;
        op[(size_t)c * HW_ + hw0 + lo] = t[lo][c];
    }
}

// Row scans: grid 128 = s(2) x b(8) x wb(8 of width 16). 1 wave/block.
// dT written in [W][H][C] layout for colscan.
__global__ __launch_bounds__(64) void k_rowscan(
        const unsigned short* __restrict__ x2, const unsigned short* __restrict__ y2b,
        const float* __restrict__ Wc, const float* __restrict__ bc,
        unsigned short* __restrict__ hs2, unsigned short* __restrict__ hn2) {
    int bid = blockIdx.x;
    int s = bid >> 6, b = (bid >> 3) & 7, wb = bid & 7;
    int w0 = wb * 16;
    int lane = threadIdx.x, q = lane >> 4, n = lane & 15;
    int ka = s ? 8 : 0, kb = ka + 1;

    bfrag WaF[4][2], WbF[4][2];
#pragma unroll
    for (int mt = 0; mt < 4; mt++)
#pragma unroll
        for (int kc = 0; kc < 2; kc++) {
            const float* wp = Wc + (size_t)(ka * 64 + mt * 16 + n) * 64 + kc * 32 + q * 8;
            WaF[mt][kc] = packf(*(const float4*)wp, *(const float4*)(wp + 4));
            const float* wq2 = Wc + (size_t)(kb * 64 + mt * 16 + n) * 64 + kc * 32 + q * 8;
            WbF[mt][kc] = packf(*(const float4*)wq2, *(const float4*)(wq2 + 4));
        }
    f4_t baR[4], bbR[4];
#pragma unroll
    for (int mt = 0; mt < 4; mt++) {
        float4 ta = *(const float4*)&bc[ka * 64 + mt * 16 + q * 4];
        float4 tb = *(const float4*)&bc[kb * 64 + mt * 16 + q * 4];
        baR[mt] = f4_t{ta.x, ta.y, ta.z, ta.w};
        bbR[mt] = f4_t{tb.x, tb.y, tb.z, tb.w};
    }

    const unsigned short* xb = x2 + (size_t)b * CHW_;
    const unsigned short* yb = y2b + (size_t)b * CHW_;
    unsigned short* dT = (s ? hn2 : hs2) + (size_t)b * CHW_;

    __shared__ __align__(16) unsigned short stt[2][16][72];

    int row0 = s ? 127 : 0;
    {
        const unsigned short* sp = xb + (size_t)(row0 * 128 + w0 + n) * 64 + q * 16;
        uint4 v0 = *(const uint4*)sp;
        uint4 v1 = *(const uint4*)(sp + 8);
        if (s) { v0 = relu8(v0); v1 = relu8(v1); }
        *(uint4*)&stt[0][n][q * 16] = v0;
        *(uint4*)&stt[0][n][q * 16 + 8] = v1;
        // WHC write
        unsigned short* op = dT + ((size_t)(w0 + n) * 128 + row0) * 64 + q * 16;
        *(uint4*)op = v0;
        *(uint4*)(op + 8) = v1;
    }

    // prefetch i=1
    uint4 xf0, xf1; ushort4 yv[4];
    {
        int row1 = s ? 126 : 1;
        const unsigned short* sp = xb + (size_t)(row1 * 128 + w0 + n) * 64 + q * 8;
        xf0 = *(const uint4*)sp;
        xf1 = *(const uint4*)(sp + 32);
#pragma unroll
        for (int mt = 0; mt < 4; mt++)
            yv[mt] = *(const ushort4*)&yb[(size_t)(row0 * 128 + w0 + n) * 64 + mt * 16 + q * 4];
    }
    WAVE_LDS_FENCE();

    for (int i = 1; i < 128; i++) {
        int row = s ? 127 - i : i;
        int rd = (i - 1) & 1, wr = i & 1;

        bfrag fb0 = *(const bfrag*)&stt[rd][n][q * 8];
        bfrag fb1 = *(const bfrag*)&stt[rd][n][32 + q * 8];
        bfrag fa0 = *(const bfrag*)&xf0;
        bfrag fa1 = *(const bfrag*)&xf1;

        f4_t DA[4], DB[4];
#pragma unroll
        for (int mt = 0; mt < 4; mt++) {
            DA[mt] = MFMA(WaF[mt][0], fa0, baR[mt], 0, 0, 0);
            DA[mt] = MFMA(WaF[mt][1], fa1, DA[mt], 0, 0, 0);
            DB[mt] = MFMA(WbF[mt][0], fb0, bbR[mt], 0, 0, 0);
            DB[mt] = MFMA(WbF[mt][1], fb1, DB[mt], 0, 0, 0);
        }

        // reload x for i+1 right after consumption (no copies)
        if (i < 127) {
            int rowN = s ? 127 - (i + 1) : i + 1;
            const unsigned short* sp = xb + (size_t)(rowN * 128 + w0 + n) * 64 + q * 8;
            xf0 = *(const uint4*)sp;
            xf1 = *(const uint4*)(sp + 32);
        }

        // h-compute consumes yv (loaded last iter)
        float h[4][4];
#pragma unroll
        for (int mt = 0; mt < 4; mt++) {
            h[mt][0] = fmaxf(fmaf(DB[mt][0], b2f(yv[mt].x), DA[mt][0]), 0.f);
            h[mt][1] = fmaxf(fmaf(DB[mt][1], b2f(yv[mt].y), DA[mt][1]), 0.f);
            h[mt][2] = fmaxf(fmaf(DB[mt][2], b2f(yv[mt].z), DA[mt][2]), 0.f);
            h[mt][3] = fmaxf(fmaf(DB[mt][3], b2f(yv[mt].w), DA[mt][3]), 0.f);
        }

        // reload y for i+1 BEFORE the stores (no store-gating next iter)
        if (i < 127) {
            int rowN = s ? 127 - (i + 1) : i + 1;
            int yrowN = s ? rowN + 1 : rowN - 1;
#pragma unroll
            for (int mt = 0; mt < 4; mt++)
                yv[mt] = *(const ushort4*)&yb[(size_t)(yrowN * 128 + w0 + n) * 64 + mt * 16 + q * 4];
        }

        // pack + state write + output store
#pragma unroll
        for (int mt = 0; mt < 4; mt++) {
            uint2 pk; pk.x = cvtpk(h[mt][0], h[mt][1]); pk.y = cvtpk(h[mt][2], h[mt][3]);
            *(uint2*)&stt[wr][n][mt * 16 + q * 4] = pk;
            *(uint2*)&dT[((size_t)(w0 + n) * 128 + row) * 64 + mt * 16 + q * 4] = pk;
        }
        WAVE_LDS_FENCE();
    }
}

// Col scans: grid 32 = d(4) x b(8). 1024 threads = 16 waves = 4 waves/SIMD.
// Wave = (rg = wave&7, ch = wave>>3); each computes 32 of 64 out-channels of
// its 16 rows. ONE barrier per step, AFTER the stt writes: all stt reads
// (fb full-row incl. partner's half, ft cross-wave) happen at step start.
__global__ __launch_bounds__(1024, 1) void k_colscan(
        const unsigned short* __restrict__ y2t,
        const unsigned short* __restrict__ hs2, const unsigned short* __restrict__ hn2,
        const float* __restrict__ Wc, const float* __restrict__ bc,
        const float* __restrict__ gam,
        unsigned short* __restrict__ outD) {
    int bid = blockIdx.x;
    int d = bid >> 3, b = bid & 7;
    int tid = threadIdx.x;
    int wave = tid >> 6, lane = tid & 63, q = lane >> 4, n = lane & 15;
    int rg = wave & 7, ch = wave >> 3;
    int row = rg * 16 + n;
    int down = (d < 2) ? 1 : 0;
    int flip = d & 1;
    const unsigned short* base2 = ((d < 2) ? hs2 : hn2) + (size_t)b * CHW_;
    int kt, ka, kb;
    if (d == 0)      { kt = 2;  ka = 3;  kb = 4;  }
    else if (d == 1) { kt = 5;  ka = 6;  kb = 7;  }
    else if (d == 2) { kt = 10; ka = 11; kb = 12; }
    else             { kt = 13; ka = 14; kb = 15; }
    float g = gam[d];

    // this wave's 2 out-channel tiles: mtg = ch*2 + mt
    bfrag WA[2][2], WB[2][2], WT[2][2];
#pragma unroll
    for (int mt = 0; mt < 2; mt++) {
        int mtg = ch * 2 + mt;
#pragma unroll
        for (int kc = 0; kc < 2; kc++) {
            const float* wa = Wc + (size_t)(ka * 64 + mtg * 16 + n) * 64 + kc * 32 + q * 8;
            const float* wb = Wc + (size_t)(kb * 64 + mtg * 16 + n) * 64 + kc * 32 + q * 8;
            const float* wt = Wc + (size_t)(kt * 64 + mtg * 16 + n) * 64 + kc * 32 + q * 8;
            WA[mt][kc] = packf(*(const float4*)wa, *(const float4*)(wa + 4));
            WB[mt][kc] = packf(*(const float4*)wb, *(const float4*)(wb + 4));
            WT[mt][kc] = packfs(*(const float4*)wt, *(const float4*)(wt + 4), g);
        }
    }
    bool bz = down ? (row == 0) : (row == 127);
    f4_t bAr[2], bBr[2], bTr[2];
#pragma unroll
    for (int mt = 0; mt < 2; mt++) {
        int mtg = ch * 2 + mt;
        float4 ta = *(const float4*)&bc[ka * 64 + mtg * 16 + q * 4];
        float4 tb = *(const float4*)&bc[kb * 64 + mtg * 16 + q * 4];
        float4 tt = *(const float4*)&bc[kt * 64 + mtg * 16 + q * 4];
        bAr[mt] = f4_t{ta.x, ta.y, ta.z, ta.w};
        bBr[mt] = f4_t{tb.x, tb.y, tb.z, tb.w};
        float gm = bz ? 0.f : g;
        bTr[mt] = f4_t{gm * tt.x, gm * tt.y, gm * tt.z, gm * tt.w};
    }

    const unsigned short* yB = y2t + (size_t)b * CHW_;
    unsigned short* oB = outD + (size_t)d * TOT_ + (size_t)b * CHW_;

    __shared__ __align__(16) unsigned short stt[2][130][64];
    for (int idx = tid; idx < 2 * 2 * 64; idx += 1024) {
        int buf = idx >> 7, hi = (idx >> 6) & 1, t = idx & 63;
        stt[buf][hi ? 129 : 0][t] = 0;
    }

    // ---- j = 0 : c0 = relu(base col0); each half-wave handles 32 shorts
    int c0 = flip ? 127 : 0;
    {
        const unsigned short* sp = base2 + (size_t)c0 * 8192 + row * 64 + ch * 32 + q * 8;
        uint4 v0 = relu8(*(const uint4*)sp);
        *(uint4*)&stt[0][row + 1][swz(row + 1, ch * 32 + q * 8)] = v0;
        unsigned short* op = oB + (size_t)(row * 128 + c0) * 64 + ch * 32 + q * 8;
        *(uint4*)op = v0;
    }

    int srow = down ? row : row + 2;
    int rsh = row + (down ? -1 : 1);
    rsh = rsh < 0 ? 0 : (rsh > 127 ? 127 : rsh);

    // initial loads: pb = base col c(1) (full 64ch B operand); yr/ys = this
    // half's 8 channels (use-order, single 16B each)
    uint4 pb0, pb1, yr, ys;
    {
        int c1 = flip ? 126 : 1;
        const unsigned short* sp = base2 + (size_t)c1 * 8192 + row * 64 + q * 8;
        pb0 = *(const uint4*)sp;
        pb1 = *(const uint4*)(sp + 32);
        int yc1 = flip ? 127 : 0;
        yr = *(const uint4*)(yB + (size_t)yc1 * 8192 + row * 64 + q * 16 + ch * 8);
        ys = *(const uint4*)(yB + (size_t)yc1 * 8192 + rsh * 64 + q * 16 + ch * 8);
    }
    LDS_BARRIER();   // covers j=0 staging for all waves

    for (int j = 1; j < 128; j++) {
        int cj = flip ? 127 - j : j;
        int rd = (j - 1) & 1, wr = j & 1;

        // step start: ALL stt reads (behind the end-of-previous-step barrier)
        bfrag fb0 = *(const bfrag*)&stt[rd][row + 1][swz(row + 1, q * 8)];
        bfrag fb1 = *(const bfrag*)&stt[rd][row + 1][swz(row + 1, 32 + q * 8)];
        bfrag ft0 = *(const bfrag*)&stt[rd][srow][swz(srow, q * 8)];
        bfrag ft1 = *(const bfrag*)&stt[rd][srow][swz(srow, 32 + q * 8)];
        bfrag fa0 = *(const bfrag*)&pb0;
        bfrag fa1 = *(const bfrag*)&pb1;

        f4_t DA[2], DB[2], DT[2];
#pragma unroll
        for (int mt = 0; mt < 2; mt++) {
            DA[mt] = MFMA(WA[mt][0], fa0, bAr[mt], 0, 0, 0);
            DA[mt] = MFMA(WA[mt][1], fa1, DA[mt], 0, 0, 0);
            DB[mt] = MFMA(WB[mt][0], fb0, bBr[mt], 0, 0, 0);
            DB[mt] = MFMA(WB[mt][1], fb1, DB[mt], 0, 0, 0);
            DT[mt] = MFMA(WT[mt][0], ft0, bTr[mt], 0, 0, 0);
            DT[mt] = MFMA(WT[mt][1], ft1, DT[mt], 0, 0, 0);
        }

        // reload pb <- base col c(j+1) right after consumption
        if (j < 127) {
            int cN = flip ? 126 - j : j + 1;
            const unsigned short* sp = base2 + (size_t)cN * 8192 + row * 64 + q * 8;
            pb0 = *(const uint4*)sp;
            pb1 = *(const uint4*)(sp + 32);
        }

        // h-compute consumes yr/ys (loaded last iter); component map:
        // yr.x=(mt0,r01) yr.y=(mt0,r23) yr.z=(mt1,r01) yr.w=(mt1,r23)
        float h[2][4];
#pragma unroll
        for (int mt = 0; mt < 2; mt++) {
            unsigned int ur0 = mt ? yr.z : yr.x, ur1 = mt ? yr.w : yr.y;
            unsigned int us0 = mt ? ys.z : ys.x, us1 = mt ? ys.w : ys.y;
            h[mt][0] = fmaxf(fmaf(DT[mt][0], blo(us0), fmaf(DB[mt][0], blo(ur0), DA[mt][0])), 0.f);
            h[mt][1] = fmaxf(fmaf(DT[mt][1], bhi(us0), fmaf(DB[mt][1], bhi(ur0), DA[mt][1])), 0.f);
            h[mt][2] = fmaxf(fmaf(DT[mt][2], blo(us1), fmaf(DB[mt][2], blo(ur1), DA[mt][2])), 0.f);
            h[mt][3] = fmaxf(fmaf(DT[mt][3], bhi(us1), fmaf(DB[mt][3], bhi(ur1), DA[mt][3])), 0.f);
        }

        // reload yr/ys <- y col yc(j+1) BEFORE any store (no store-gating)
        if (j < 127) {
            int ycN = flip ? 127 - j : j;
            yr = *(const uint4*)(yB + (size_t)ycN * 8192 + row * 64 + q * 16 + ch * 8);
            ys = *(const uint4*)(yB + (size_t)ycN * 8192 + rsh * 64 + q * 16 + ch * 8);
        }

        // pack + state write + output store (this half's 2 tiles)
#pragma unroll
        for (int mt = 0; mt < 2; mt++) {
            int mtg = ch * 2 + mt;
            uint2 pk; pk.x = cvtpk(h[mt][0], h[mt][1]); pk.y = cvtpk(h[mt][2], h[mt][3]);
            *(uint2*)&stt[wr][row + 1][swz(row + 1, mtg * 16 + q * 4)] = pk;
            *(uint2*)&oB[(size_t)(row * 128 + cj) * 64 + mtg * 16 + q * 4] = pk;
        }

        LDS_BARRIER();   // publish state(j) to ALL waves before step j+1 reads
    }
}

extern "C" void kernel_launch(void* const* d_in, const int* in_sizes, int n_in,
                              void* d_out, int out_size, void* d_ws, size_t ws_size,
                              hipStream_t stream) {
    const float* x   = (const float*)d_in[0];
    const float* y   = (const float*)d_in[1];
    const float* Wc  = (const float*)d_in[2];
    const float* bc  = (const float*)d_in[3];
    const float* gam = (const float*)d_in[4];
    float* out = (float*)d_out;

    // ws (all bf16): x2, y2b, y2t, hs2, hn2 (TOT_ each), outD (4x TOT_) = 151MB
    unsigned short* x2   = (unsigned short*)d_ws;
    unsigned short* y2b  = x2 + (size_t)TOT_;
    unsigned short* y2t  = y2b + (size_t)TOT_;
    unsigned short* hs2  = y2t + (size_t)TOT_;
    unsigned short* hn2  = hs2 + (size_t)TOT_;
    unsigned short* outD = hn2 + (size_t)TOT_;

    hipLaunchKernelGGL(k_prep, dim3(4096), dim3(256), 0, stream, x, y, y2b, x2, y2t);
    hipLaunchKernelGGL(k_rowscan, dim3(128), dim3(64), 0, stream, x2, y2b, Wc, bc, hs2, hn2);
    hipLaunchKernelGGL(k_colscan, dim3(32), dim3(1024), 0, stream, y2t, hs2, hn2, Wc, bc, gam, outD);
    hipLaunchKernelGGL(k_tb, dim3(2048), dim3(256), 0, stream,
                       outD, outD + (size_t)TOT_, outD + 2 * (size_t)TOT_,
                       outD + 3 * (size_t)TOT_, out);
}